// Round 6
// baseline (47.691 us; speedup 1.0000x reference)
//
#include <hip/hip_runtime.h>

// PCEN: EMA over time then (x / (M+eps)^alpha + delta)^r - delta^r
// x: [B=64, T=2048, F=128] float32, out same shape/type.
//
// Exact 2-kernel chunked scan (EMA is affine: m_end = a^L * m_in + local):
//  K1: thread=(b,c,f) computes local chunk carry from 0-init (chunk 0 exact
//      via m[0]=x[0]); f in the lane index -> coalesced; unroll 16 so ~16
//      loads stay in flight per thread (R2 lesson: short lookahead on these
//      dependent-FMA streams goes latency-bound).
//  K2: thread=(b,c,f) composes its own carry-in inline (<=31 L2-hot
//      coalesced loads + FMAs, wave-uniform trip count), replays the chunk,
//      emits PCEN with nontemporal stores (out never re-read).
//
// Cooperative/grid.sync() abandoned: R5's launch silently no-op'd (absmax
// == max|ref|). The 3-kernel R4 version passed at 46 us; this removes the
// k_prefix dispatch, one graph edge, and the 2 MB m_in round-trip.

namespace {
constexpr int B = 64;
constexpr int T = 2048;
constexpr int F = 128;
constexpr int CH = 32;        // chunks per sequence
constexpr int L = T / CH;     // 64
constexpr float S   = 0.025f;
constexpr float A1  = 0.975f;
constexpr float AL  = 0.19779136545478059f;  // 0.975^64
constexpr float EPS = 1e-6f;
constexpr float ALPHA = 0.98f;
constexpr float DR  = 1.1892071150027210667f;  // 2^0.25
}

__global__ __launch_bounds__(256) void k_carry(const float* __restrict__ x,
                                               float* __restrict__ carry) {
    const int tid = blockIdx.x * 256 + threadIdx.x;   // [b][c][f], f fastest
    const int f  = tid & (F - 1);
    const int cb = tid >> 7;
    const int c  = cb & (CH - 1);
    const int b  = cb >> 5;

    const float* p = x + ((size_t)(b * T + c * L)) * F + f;
    float m = (c == 0) ? p[0] : 0.0f;   // c==0: update at t=0 re-yields x[0]
    #pragma unroll 16
    for (int t = 0; t < L; ++t) {
        float xv = p[(size_t)t * F];
        m = fmaf(A1, m, S * xv);
    }
    carry[tid] = m;                      // layout [b][c][f]
}

__global__ __launch_bounds__(256) void k_final(const float* __restrict__ x,
                                               const float* __restrict__ carry,
                                               float* __restrict__ out) {
    const int tid = blockIdx.x * 256 + threadIdx.x;
    const int f  = tid & (F - 1);
    const int cb = tid >> 7;
    const int c  = cb & (CH - 1);
    const int b  = cb >> 5;

    const size_t base = ((size_t)(b * T + c * L)) * F + f;
    const float* p = x + base;
    float*       q = out + base;

    // ---- inline prefix: carry-in = inclusive prefix of chunks 0..c-1 ----
    // (wave-uniform c: all 64 lanes share the same trip count; loads are
    //  coalesced 256B from the 1 MiB L2-hot carry buffer)
    float m;
    if (c == 0) {
        m = p[0];                        // exact m[0] = x[0] rule
    } else {
        const float* cr = carry + (size_t)b * CH * F + f;
        float me = cr[0];
        for (int cc = 1; cc < c; ++cc)
            me = fmaf(AL, me, cr[(size_t)cc * F]);
        m = me;
    }

    // ---- replay chunk with exact carry-in, emit PCEN ----
    #pragma unroll 8
    for (int t = 0; t < L; ++t) {
        float xv = p[(size_t)t * F];
        m = fmaf(A1, m, S * xv);
        // x / (M+eps)^alpha == x * exp2(-alpha * log2(M+eps))
        float inv = exp2f(-ALPHA * log2f(m + EPS));
        float u   = fmaf(xv, inv, 2.0f);
        float r   = sqrtf(sqrtf(u)) - DR;          // u^0.25 - 2^0.25
        __builtin_nontemporal_store(r, &q[(size_t)t * F]);
    }
}

extern "C" void kernel_launch(void* const* d_in, const int* in_sizes, int n_in,
                              void* d_out, int out_size, void* d_ws, size_t ws_size,
                              hipStream_t stream) {
    const float* x   = (const float*)d_in[0];
    float*       out = (float*)d_out;
    float* carry = (float*)d_ws;                       // 1 MiB scratch

    const int total = B * CH * F;                      // 262144 threads
    k_carry<<<dim3(total / 256), dim3(256), 0, stream>>>(x, carry);
    k_final<<<dim3(total / 256), dim3(256), 0, stream>>>(x, carry, out);
}